// Round 8
// baseline (201.903 us; speedup 1.0000x reference)
//
#include <hip/hip_runtime.h>
#include <hip/hip_bf16.h>
#include <math.h>

// Problem constants
#define B_ 2
#define S_ 2048
#define D_ 1024
#define H_ 16
#define HD_ 64
#define BHS (B_*H_*S_)          // 65536 rows of [HD]
#define NROWS (B_*S_)           // 4096 token rows

typedef __attribute__((ext_vector_type(8))) short bf16x8;
typedef __attribute__((ext_vector_type(4))) short bf16x4;
typedef __attribute__((ext_vector_type(4))) float f32x4;
typedef __attribute__((ext_vector_type(4))) int i32x4;

#ifdef __HIP_DEVICE_COMPILE__
#define EXP2(x) __builtin_amdgcn_exp2f(x)
#else
#define EXP2(x) exp2f(x)
#endif

#define MFMA32(a, b, c) __builtin_amdgcn_mfma_f32_16x16x32_bf16(a, b, c, 0, 0, 0)

// SCALE * log2(e) = 0.125 * 1.4426950408889634  (folded into stored Q)
#define SCALE_LOG2E 0.18033688011112043f

// counted-vmcnt phase primitives: the wait at a phase top targets loads
// issued ONE FULL PHASE earlier; fresh prefetches are never drained.
#define VMCNT(N) asm volatile("s_waitcnt vmcnt(" #N ")" ::: "memory")
#define SBAR() do { __builtin_amdgcn_s_barrier(); \
                    __builtin_amdgcn_sched_barrier(0); } while (0)
#define SCHED0() __builtin_amdgcn_sched_barrier(0)

__device__ __forceinline__ short f2bf(float x) {
  __hip_bfloat16 h = __float2bfloat16(x);
  return *reinterpret_cast<short*>(&h);
}
// pack two floats to a packed bf16 pair, round-half-away: 3 VALU ops
__device__ __forceinline__ int packbf_hu(float lo, float hi) {
  unsigned lb = __float_as_uint(lo) + 0x8000u;
  unsigned hb = __float_as_uint(hi) + 0x8000u;
  return (int)__builtin_amdgcn_perm(hb, lb, 0x07060302u);
}

// async 16B global -> LDS (hardware adds lane*16 to the wave-uniform base)
__device__ __forceinline__ void gload_lds16(const short* g, short* l) {
  __builtin_amdgcn_global_load_lds(
      (const __attribute__((address_space(1))) void*)g,
      (__attribute__((address_space(3))) void*)l, 16, 0, 0);
}

// ---------------------------------------------------------------------------
// prep: fused fp32->bf16 casts (tokens, qkv_w, out_w) + RoPE sin/cos table.
// ---------------------------------------------------------------------------
__global__ __launch_bounds__(256) void prep(
    const float* __restrict__ tokens, const float* __restrict__ qkv_w,
    const float* __restrict__ out_w, short* __restrict__ tok_bf,
    short* __restrict__ qkvw_bf, short* __restrict__ outw_bf,
    float* __restrict__ tab) {
  const int i = blockIdx.x * 256 + threadIdx.x;
  const float* src;
  short* dst;
  int j;
  if (i < 524288) {
    src = tokens; dst = tok_bf; j = i;
  } else if (i < 917504) {
    src = qkv_w; dst = qkvw_bf; j = i - 524288;
  } else if (i < 1048576) {
    src = out_w; dst = outw_bf; j = i - 917504;
  } else if (i < 1056768) {
    const int e = (i - 1048576) * 8;     // entry = s*32 + f
    const int s = e >> 5;
    const int f0 = e & 31;
#pragma unroll
    for (int k = 0; k < 8; k++) {
      const int f = f0 + k;
      const float theta = (float)s * exp2f(-(float)f * 0.41524101186092034f);
      float sn, cs;
      sincosf(theta, &sn, &cs);
      tab[(s * 32 + f) * 2] = sn;
      tab[(s * 32 + f) * 2 + 1] = cs;
    }
    return;
  } else {
    return;
  }
  const float4 a = *(const float4*)(src + (long)j * 8);
  const float4 b = *(const float4*)(src + (long)j * 8 + 4);
  short tmp[8] = {f2bf(a.x), f2bf(a.y), f2bf(a.z), f2bf(a.w),
                  f2bf(b.x), f2bf(b.y), f2bf(b.z), f2bf(b.w)};
  *(bf16x8*)(dst + (long)j * 8) = *(const bf16x8*)tmp;
}

// ---------------------------------------------------------------------------
// qkv projection: 128x128 tile, 4 waves (2x2, wave piece 64x64), BK=64,
// counted 2-buf schedule (unchanged).
// ---------------------------------------------------------------------------
__global__ __launch_bounds__(256) void qkv_mfma(
    const short* __restrict__ A, const short* __restrict__ W,
    const float* __restrict__ bias, const float* __restrict__ tab,
    short* __restrict__ qb, short* __restrict__ kb, short* __restrict__ vtb) {
  __shared__ short smem[32768];   // 2 bufs x (As 8192 | Bs 8192); epi overlay
  const int t = threadIdx.x;
  const int w = t >> 6;
  const int lane = t & 63;
  const int col = lane & 15;
  const int quad = lane >> 4;
  const int wm = w >> 1;
  const int wn = w & 1;
  const int bid = blockIdx.x;     // 0..767
  const int xcd = bid & 7;
  const int seq = bid >> 3;       // 0..95
  const int m0 = (seq / 3) * 128;
  const int n0 = (xcd * 3 + seq % 3) * 128;

  f32x4 acc[4][4] = {};

  auto stage = [&](short* As, short* Bs, int k0) {
#pragma unroll
    for (int i = 0; i < 4; i++) {  // A: 1024 chunks of 16B (128 rows x 8)
      const int c0 = i * 256 + w * 64;
      const int c = c0 + lane;
      const int row = c >> 3;
      const int gseg = (c & 7) ^ (row & 7);
      gload_lds16(&A[(m0 + row) * 1024 + k0 + gseg * 8], As + c0 * 8);
    }
#pragma unroll
    for (int i = 0; i < 4; i++) {  // B: 1024 chunks
      const int c0 = i * 256 + w * 64;
      const int c = c0 + lane;
      const int row = c >> 3;
      const int gseg = (c & 7) ^ (row & 7);
      gload_lds16(&W[(n0 + row) * 1024 + k0 + gseg * 8], Bs + c0 * 8);
    }
  };

  auto compute = [&](const short* As, const short* Bs) {
#pragma unroll
    for (int half = 0; half < 2; half++) {
      bf16x8 af[4], bfr[4];
#pragma unroll
      for (int mt = 0; mt < 4; mt++) {
        const int m = wm * 64 + mt * 16 + col;
        af[mt] =
            *(const bf16x8*)&As[m * 64 + (((quad + half * 4) ^ (m & 7)) * 8)];
      }
#pragma unroll
      for (int nt = 0; nt < 4; nt++) {
        const int n = wn * 64 + nt * 16 + col;
        bfr[nt] =
            *(const bf16x8*)&Bs[n * 64 + (((quad + half * 4) ^ (n & 7)) * 8)];
      }
#pragma unroll
      for (int mt = 0; mt < 4; mt++)
#pragma unroll
        for (int nt = 0; nt < 4; nt++)
          acc[mt][nt] = MFMA32(af[mt], bfr[nt], acc[mt][nt]);
    }
  };

  short* As0 = smem;          short* Bs0 = smem + 8192;
  short* As1 = smem + 16384;  short* Bs1 = smem + 24576;

  stage(As0, Bs0, 0);
  for (int it = 0; it < 8; it++) {
    const int k = it * 128;
    VMCNT(0); SBAR();               // waits stage(t), issued a full phase ago
    stage(As1, Bs1, k + 64);
    SCHED0();                       // pin prefetch-issue before compute
    compute(As0, Bs0);
    VMCNT(0); SBAR();
    if (it < 7) stage(As0, Bs0, k + 128);
    SCHED0();
    compute(As1, Bs1);
  }
  __syncthreads();   // all compute done everywhere; epilogue overlay valid

  const int j_base = n0 + wn * 64;    // 64-aligned -> single (c,h), uniform/wave
  const int c = j_base >> 10;
  const int h = (j_base >> 6) & 15;
  float bi[4];
#pragma unroll
  for (int nt = 0; nt < 4; nt++) bi[nt] = bias[j_base + nt * 16 + col];

  if (c < 2) {
    // ---- q/k: per-wave 16-row LDS transpose + fused RoPE + L2 norm ----
    short* dst = (c == 0) ? qb : kb;
    float* Tf = (float*)smem + w * 1088;           // 16 x 68 fp32, per wave
#pragma unroll
    for (int mt = 0; mt < 4; mt++) {
#pragma unroll
      for (int nt = 0; nt < 4; nt++)
#pragma unroll
        for (int r = 0; r < 4; r++)
          Tf[(quad * 4 + r) * 68 + nt * 16 + col] = acc[mt][nt][r] + bi[nt];
      // wave-private round trip (same-wave LDS ops are ordered)
#pragma unroll
      for (int p = 0; p < 4; p++) {
        const int rloc = p * 4 + quad;
        const int n = m0 + wm * 64 + mt * 16 + rloc;
        const int bidx = n >> 11;
        const int s = n & 2047;
        const float4 xv = *(const float4*)&Tf[rloc * 68 + col * 4];
        const float4 tc = *(const float4*)&tab[s * 64 + col * 4];
        const float e0 = xv.x * tc.y - xv.y * tc.x;
        const float o0 = xv.x * tc.x + xv.y * tc.y;
        const float e1 = xv.z * tc.w - xv.w * tc.z;
        const float o1 = xv.z * tc.z + xv.w * tc.w;
        float ss = e0 * e0 + o0 * o0 + e1 * e1 + o1 * o1;
        ss += __shfl_xor(ss, 1, 64);
        ss += __shfl_xor(ss, 2, 64);
        ss += __shfl_xor(ss, 4, 64);
        ss += __shfl_xor(ss, 8, 64);
        float scl = 1.0f / fmaxf(sqrtf(ss), 1e-12f);
        if (c == 0) scl *= SCALE_LOG2E;   // fold attn scale into stored Q
        int2 pk;
        pk.x = packbf_hu(e0 * scl, o0 * scl);
        pk.y = packbf_hu(e1 * scl, o1 * scl);
        *(int2*)&dst[((long)(bidx * 16 + h) * 2048 + s) * 64 + col * 4] = pk;
      }
      // next mt reuses Tf: same-wave in-order LDS ops, no barrier needed
    }
  } else {
    // ---- v: blocked-vt stores, b128-paired layout (one 16B slot holds the
    // two 16-key chunks of a 32-key MFMA group); int4 stores coalesced.
    const int bidx = m0 >> 11;
    const int st = ((m0 & 2047) >> 6) + wm;
    short* vbase = vtb + ((long)(bidx * 16 + h) * 32 + st) * 4096;
#pragma unroll
    for (int mtp = 0; mtp < 2; mtp++)
#pragma unroll
      for (int ntq = 0; ntq < 4; ntq++) {
        int4 pk4;
        pk4.x = packbf_hu(acc[2 * mtp][ntq][0] + bi[ntq],
                          acc[2 * mtp][ntq][1] + bi[ntq]);
        pk4.y = packbf_hu(acc[2 * mtp][ntq][2] + bi[ntq],
                          acc[2 * mtp][ntq][3] + bi[ntq]);
        pk4.z = packbf_hu(acc[2 * mtp + 1][ntq][0] + bi[ntq],
                          acc[2 * mtp + 1][ntq][1] + bi[ntq]);
        pk4.w = packbf_hu(acc[2 * mtp + 1][ntq][2] + bi[ntq],
                          acc[2 * mtp + 1][ntq][3] + bi[ntq]);
        *(int4*)&vbase[(mtp * 4 + ntq) * 512 + quad * 128 + col * 8] = pk4;
      }
  }
}

// ---------------------------------------------------------------------------
// MFMA streaming attention. NEW this round: V READ DIRECT FROM GLOBAL.
// The PV read pattern over the staged V buffer was byte-linear in lane and
// the staged buffer was a verbatim copy of the global blocked-vt tile — the
// LDS round-trip bought nothing. Reading va from global (coalesced 1KB/wave,
// L1/L2-served, tile shared by 8 waves) halves LDS read traffic (the binding
// resource: K+V reads were ~20us/CU) and halves staging writes. K stays in
// LDS (its fragment pattern is stride-128B from global — the R4 failure).
// LDS 65536 -> 35328 B. Everything else identical to round 7.
// ---------------------------------------------------------------------------
__global__ __launch_bounds__(512) void attn_mfma(
    const short* __restrict__ qb,  // [B,H,S,64]  (pre-scaled by SCALE*log2e)
    const short* __restrict__ kb,  // [B,H,S,64]
    const short* __restrict__ vt,  // [B,H,32 tiles,4096] blocked+paired
    short* __restrict__ ob) {      // [B,H,S,64]
  __shared__ __align__(16) char smem[35328];   // K staging; epilogue overlay
  short* Ks = (short*)smem;            // [buf][grp][4096 shorts]
  const int t = threadIdx.x;
  const int w = t >> 6;            // 0..7
  const int grp = w >> 2;          // key-split group (2 groups x 4 waves)
  const int wl = w & 3;            // wave within group
  const int lane = t & 63;
  const int col = lane & 15;
  const int quad = lane >> 4;
  const int bh = blockIdx.x;
  const int q0 = blockIdx.y * 128;
  const long hb = (long)bh * S_ * 64;
  const short* kg = kb + hb;
  const short* vg = vt + (long)bh * 64 * S_;

  bf16x8 qa[2][2];
#pragma unroll
  for (int mt2 = 0; mt2 < 2; mt2++)
#pragma unroll
    for (int h = 0; h < 2; h++)
      qa[mt2][h] = *(const bf16x8*)&qb[hb +
          (long)(q0 + wl * 32 + mt2 * 16 + col) * 64 + h * 32 + quad * 8];

  const int tt = (wl << 6) | lane;   // 0..255 within group
  int kofs[2];
#pragma unroll
  for (int i = 0; i < 2; i++) {
    const int cc = tt + 256 * i;
    kofs[i] = ((cc >> 7) * 16 + (cc & 15)) * 64 + ((cc >> 6) & 1) * 32 +
              ((cc >> 4) & 3) * 8;
  }

  short* KfL0 = Ks + grp * 4096;    // buf0 (constant offset from buf1)
  short* KfL1 = KfL0 + 8192;

  f32x4 oacc[2][4] = {};
  f32x4 lacc[2] = {};
  const short oneb = 0x3F80;   // bf16 1.0
  const bf16x8 ones8 = {oneb, oneb, oneb, oneb, oneb, oneb, oneb, oneb};

  auto stage = [&](short* KfL, int kt) {     // K only
    const short* kgp = kg + (long)kt * 64;
#pragma unroll
    for (int i = 0; i < 2; i++)
      gload_lds16(kgp + kofs[i], KfL + i * 2048 + wl * 512);
  };

  auto compute = [&](const short* KfL, const short* Vt) {
#pragma unroll
    for (int ntp = 0; ntp < 2; ntp++) {
      i32x4 pw[2];
#pragma unroll
      for (int half = 0; half < 2; half++) {
        const int nt = ntp * 2 + half;
        const bf16x8 ka0 =
            *(const bf16x8*)&KfL[nt * 1024 + quad * 128 + col * 8];
        const bf16x8 ka1 =
            *(const bf16x8*)&KfL[nt * 1024 + 512 + quad * 128 + col * 8];
#pragma unroll
        for (int mt2 = 0; mt2 < 2; mt2++) {
          f32x4 z = {0.f, 0.f, 0.f, 0.f};
          z = MFMA32(ka0, qa[mt2][0], z);
          z = MFMA32(ka1, qa[mt2][1], z);
          const float e0 = EXP2(z[0]);   // scale pre-folded into Q
          const float e1 = EXP2(z[1]);
          const float e2 = EXP2(z[2]);
          const float e3 = EXP2(z[3]);
          if (half == 0) {
            pw[mt2].x = packbf_hu(e0, e1);
            pw[mt2].y = packbf_hu(e2, e3);
          } else {
            pw[mt2].z = packbf_hu(e0, e1);
            pw[mt2].w = packbf_hu(e2, e3);
          }
        }
      }
      const bf16x8 pb0 = __builtin_bit_cast(bf16x8, pw[0]);
      const bf16x8 pb1 = __builtin_bit_cast(bf16x8, pw[1]);
      lacc[0] = MFMA32(ones8, pb0, lacc[0]);   // 32-key row-sum, matrix pipe
      lacc[1] = MFMA32(ones8, pb1, lacc[1]);
      __builtin_amdgcn_s_setprio(1);           // MFMA-dominated PV cluster
#pragma unroll
      for (int dt = 0; dt < 4; dt++) {
        const bf16x8 va = *(const bf16x8*)      // DIRECT GLOBAL READ (coalesced)
            &Vt[(ntp * 4 + dt) * 512 + quad * 128 + col * 8];
        oacc[0][dt] = MFMA32(va, pb0, oacc[0][dt]);
        oacc[1][dt] = MFMA32(va, pb1, oacc[1][dt]);
      }
      __builtin_amdgcn_s_setprio(0);
    }
  };

  const int base = grp * 1024;
  stage(KfL0, base);
  for (int it = 0; it < 8; it++) {       // 2 x 64-key tiles per iteration
    const int kt0 = base + it * 128;
    VMCNT(0); SBAR();                    // waits stage issued a full phase ago
    stage(KfL1, kt0 + 64);
    SCHED0();
    compute(KfL0, vg + (long)(kt0 >> 6) * 4096);
    VMCNT(0); SBAR();
    if (it < 7) stage(KfL0, kt0 + 128);
    SCHED0();
    compute(KfL1, vg + (long)((kt0 + 64) >> 6) * 4096);
  }
  __syncthreads();   // all waves done; staging dead -> overlay valid

  float* Ocomb = (float*)smem;                 // [128][68]
  float* lsumC = (float*)(smem + 34816);       // [128]
  if (grp == 1) {
#pragma unroll
    for (int mt2 = 0; mt2 < 2; mt2++) {
      const int qloc = wl * 32 + mt2 * 16 + col;
      if (quad == 0) lsumC[qloc] = lacc[mt2][0];
#pragma unroll
      for (int dt = 0; dt < 4; dt++)
        *(f32x4*)&Ocomb[qloc * 68 + dt * 16 + quad * 4] = oacc[mt2][dt];
    }
  }
  __syncthreads();
  if (grp == 0) {
#pragma unroll
    for (int mt2 = 0; mt2 < 2; mt2++) {
      const int qloc = wl * 32 + mt2 * 16 + col;
      const float inv = 1.0f / (lacc[mt2][0] + lsumC[qloc]);
      short* orow = ob + hb + (long)(q0 + qloc) * 64;
#pragma unroll
      for (int dt = 0; dt < 4; dt++) {
        const float4 oc = *(const float4*)&Ocomb[qloc * 68 + dt * 16 + quad * 4];
        int2 pk;
        pk.x = packbf_hu((oacc[mt2][dt][0] + oc.x) * inv,
                         (oacc[mt2][dt][1] + oc.y) * inv);
        pk.y = packbf_hu((oacc[mt2][dt][2] + oc.z) * inv,
                         (oacc[mt2][dt][3] + oc.w) * inv);
        *(int2*)&orow[dt * 16 + quad * 4] = pk;
      }
    }
  }
}

// ---------------------------------------------------------------------------
// out projection: 64x64 tile, 4 waves (2x2, wave piece 32x32), BK=64,
// counted 2-buf schedule (unchanged).
// ---------------------------------------------------------------------------
__global__ __launch_bounds__(256) void out_mfma(
    const short* __restrict__ O, const short* __restrict__ W,
    const float* __restrict__ bias, float* __restrict__ out) {
  __shared__ short smem[16384];   // 2 bufs x (As 4096 | Bs 4096)
  const int t = threadIdx.x;
  const int w = t >> 6;
  const int lane = t & 63;
  const int col = lane & 15;
  const int quad = lane >> 4;
  const int wm = w >> 1;
  const int wn = w & 1;
  const int bid = blockIdx.x;     // 0..1023
  const int xcd = bid & 7;
  const int seq = bid >> 3;       // 0..127
  const int m0 = (seq >> 1) * 64;
  const int n0 = (xcd * 2 + (seq & 1)) * 64;

  f32x4 acc[2][2] = {};

  auto stage = [&](short* As, short* Bs, int k0) {
#pragma unroll
    for (int i = 0; i < 2; i++) {   // A: 512 chunks (64 rows x 8)
      const int c0 = i * 256 + w * 64;
      const int c = c0 + lane;
      const int row = c >> 3;
      const int gseg = (c & 7) ^ (row & 7);
      const int n = m0 + row;
      const int bidx = n >> 11;
      const int s = n & 2047;
      const int kk = k0 + gseg * 8;
      gload_lds16(&O[((long)(bidx * 16 + (kk >> 6)) * 2048 + s) * 64 + (kk & 63)],
                  As + c0 * 8);
    }
#pragma unroll
    for (int i = 0; i < 2; i++) {   // B: 512 chunks
      const int c0 = i * 256 + w * 64;
      const int c = c0 + lane;
      const int row = c >> 3;
      const int gseg = (c & 7) ^ (row & 7);
      gload_lds16(&W[(n0 + row) * 1024 + k0 + gseg * 8], Bs + c0 * 8);
    }
  };

  auto compute = [&](const short* As, const short* Bs) {
#pragma unroll
    for (int half = 0; half < 2; half++) {
      bf16x8 af[2], bfr[2];
#pragma unroll
      for (int mt = 0; mt < 2; mt++) {
        const int m = wm * 32 + mt * 16 + col;
        af[mt] =
            *(const bf16x8*)&As[m * 64 + (((quad + half * 4) ^ (m & 7)) * 8)];
      }
#pragma unroll
      for (int nt = 0; nt < 2; nt++) {
        const int n = wn * 32 + nt * 16 + col;
        bfr[nt] =
            *(const bf16x8*)&Bs[n * 64 + (((quad + half * 4) ^ (n & 7)) * 8)];
      }
#pragma unroll
      for (int mt = 0; mt < 2; mt++)
#pragma unroll
        for (int nt = 0; nt < 2; nt++)
          acc[mt][nt] = MFMA32(af[mt], bfr[nt], acc[mt][nt]);
    }
  };

  short* As0 = smem;         short* Bs0 = smem + 4096;
  short* As1 = smem + 8192;  short* Bs1 = smem + 12288;

  stage(As0, Bs0, 0);
  for (int it = 0; it < 8; it++) {
    const int k = it * 128;
    VMCNT(0); SBAR();
    stage(As1, Bs1, k + 64);
    SCHED0();
    compute(As0, Bs0);
    VMCNT(0); SBAR();
    if (it < 7) stage(As0, Bs0, k + 128);
    SCHED0();
    compute(As1, Bs1);
  }

  float bi[2];
#pragma unroll
  for (int nt = 0; nt < 2; nt++) bi[nt] = bias[n0 + wn * 32 + nt * 16 + col];
#pragma unroll
  for (int mt = 0; mt < 2; mt++) {
#pragma unroll
    for (int r = 0; r < 4; r++) {
      const int n = m0 + wm * 32 + mt * 16 + quad * 4 + r;
#pragma unroll
      for (int nt = 0; nt < 2; nt++)
        out[(long)n * 1024 + n0 + wn * 32 + nt * 16 + col] =
            acc[mt][nt][r] + bi[nt];
    }
  }
}

// ---------------------------------------------------------------------------
extern "C" void kernel_launch(void* const* d_in, const int* in_sizes, int n_in,
                              void* d_out, int out_size, void* d_ws,
                              size_t ws_size, hipStream_t stream) {
  const float* tokens = (const float*)d_in[0];
  const float* qkv_w = (const float*)d_in[1];
  const float* qkv_b = (const float*)d_in[2];
  const float* out_w = (const float*)d_in[3];
  const float* out_b = (const float*)d_in[4];
  float* out = (float*)d_out;

  const size_t per = (size_t)BHS * HD_;          // 4,194,304 elements
  float* tab = (float*)d_ws;                     // 2048*32*2 floats = 512 KB
  short* tok_bf = (short*)(tab + 2048 * 64);
  short* qkvw_bf = tok_bf + per;                 // 3M shorts
  short* outw_bf = qkvw_bf + 3 * per / 4;        // 1M
  short* q_bf = outw_bf + per / 4;               // 4M
  short* k_bf = q_bf + per;                      // 4M
  short* vt_bf = k_bf + per;                     // 4M (blocked layout)
  short* O_bf = vt_bf + per;                     // 4M  (~48.5 MB total)

  // 1) casts + rope table
  hipLaunchKernelGGL(prep, dim3(4128), dim3(256), 0, stream, tokens, qkv_w,
                     out_w, tok_bf, qkvw_bf, outw_bf, tab);
  // 2) QKV projection (BK=64 counted 2-buf) + fused RoPE/norm + paired vt
  hipLaunchKernelGGL(qkv_mfma, dim3(768), dim3(256), 0, stream, tok_bf,
                     qkvw_bf, qkv_b, tab, q_bf, k_bf, vt_bf);
  // 3) Attention (V direct-from-global; K LDS-staged, counted schedule)
  hipLaunchKernelGGL(attn_mfma, dim3(B_ * H_, S_ / 128), dim3(512), 0, stream,
                     q_bf, k_bf, vt_bf, O_bf);
  // 4) Output projection (BK=64 counted 2-buf)
  hipLaunchKernelGGL(out_mfma, dim3(1024), dim3(256), 0, stream, O_bf,
                     outw_bf, out_b, out);
}

// Round 10
// 181.311 us; speedup vs baseline: 1.1136x; 1.1136x over previous
//
#include <hip/hip_runtime.h>
#include <hip/hip_bf16.h>
#include <math.h>

// Problem constants
#define B_ 2
#define S_ 2048
#define D_ 1024
#define H_ 16
#define HD_ 64
#define BHS (B_*H_*S_)          // 65536 rows of [HD]
#define NROWS (B_*S_)           // 4096 token rows

typedef __attribute__((ext_vector_type(8))) short bf16x8;
typedef __attribute__((ext_vector_type(4))) short bf16x4;
typedef __attribute__((ext_vector_type(4))) float f32x4;
typedef __attribute__((ext_vector_type(4))) int i32x4;

#ifdef __HIP_DEVICE_COMPILE__
#define EXP2(x) __builtin_amdgcn_exp2f(x)
#else
#define EXP2(x) exp2f(x)
#endif

#define MFMA32(a, b, c) __builtin_amdgcn_mfma_f32_16x16x32_bf16(a, b, c, 0, 0, 0)

// SCALE * log2(e) = 0.125 * 1.4426950408889634  (folded into stored Q)
#define SCALE_LOG2E 0.18033688011112043f

// counted-vmcnt phase primitives
#define VMCNT(N) asm volatile("s_waitcnt vmcnt(" #N ")" ::: "memory")
#define SBAR() do { __builtin_amdgcn_s_barrier(); \
                    __builtin_amdgcn_sched_barrier(0); } while (0)
#define SCHED0() __builtin_amdgcn_sched_barrier(0)

__device__ __forceinline__ short f2bf(float x) {
  __hip_bfloat16 h = __float2bfloat16(x);
  return *reinterpret_cast<short*>(&h);
}
// pack two floats to a packed bf16 pair, round-half-away: 3 VALU ops
__device__ __forceinline__ int packbf_hu(float lo, float hi) {
  unsigned lb = __float_as_uint(lo) + 0x8000u;
  unsigned hb = __float_as_uint(hi) + 0x8000u;
  return (int)__builtin_amdgcn_perm(hb, lb, 0x07060302u);
}

// async 16B global -> LDS (hardware adds lane*16 to the wave-uniform base)
__device__ __forceinline__ void gload_lds16(const short* g, short* l) {
  __builtin_amdgcn_global_load_lds(
      (const __attribute__((address_space(1))) void*)g,
      (__attribute__((address_space(3))) void*)l, 16, 0, 0);
}

// ---------------------------------------------------------------------------
// prep: fused fp32->bf16 casts (tokens, qkv_w, out_w) + RoPE sin/cos table.
// ---------------------------------------------------------------------------
__global__ __launch_bounds__(256) void prep(
    const float* __restrict__ tokens, const float* __restrict__ qkv_w,
    const float* __restrict__ out_w, short* __restrict__ tok_bf,
    short* __restrict__ qkvw_bf, short* __restrict__ outw_bf,
    float* __restrict__ tab) {
  const int i = blockIdx.x * 256 + threadIdx.x;
  const float* src;
  short* dst;
  int j;
  if (i < 524288) {
    src = tokens; dst = tok_bf; j = i;
  } else if (i < 917504) {
    src = qkv_w; dst = qkvw_bf; j = i - 524288;
  } else if (i < 1048576) {
    src = out_w; dst = outw_bf; j = i - 917504;
  } else if (i < 1056768) {
    const int e = (i - 1048576) * 8;     // entry = s*32 + f
    const int s = e >> 5;
    const int f0 = e & 31;
#pragma unroll
    for (int k = 0; k < 8; k++) {
      const int f = f0 + k;
      const float theta = (float)s * exp2f(-(float)f * 0.41524101186092034f);
      float sn, cs;
      sincosf(theta, &sn, &cs);
      tab[(s * 32 + f) * 2] = sn;
      tab[(s * 32 + f) * 2 + 1] = cs;
    }
    return;
  } else {
    return;
  }
  const float4 a = *(const float4*)(src + (long)j * 8);
  const float4 b = *(const float4*)(src + (long)j * 8 + 4);
  short tmp[8] = {f2bf(a.x), f2bf(a.y), f2bf(a.z), f2bf(a.w),
                  f2bf(b.x), f2bf(b.y), f2bf(b.z), f2bf(b.w)};
  *(bf16x8*)(dst + (long)j * 8) = *(const bf16x8*)tmp;
}

// ---------------------------------------------------------------------------
// qkv projection — EXACT round-7 form (passed, 174.1us total): 128x128 tile,
// 4 waves (2x2, wave piece 64x64), BK=64, 2-buf counted distance-1.
// (R9's distance-2 used BK=32 buffer offsets with BK=64 data -> LDS smash;
// distance-2 at BK=64 needs 96KB, geometrically infeasible. Reverted.)
// ---------------------------------------------------------------------------
__global__ __launch_bounds__(256) void qkv_mfma(
    const short* __restrict__ A, const short* __restrict__ W,
    const float* __restrict__ bias, const float* __restrict__ tab,
    short* __restrict__ qb, short* __restrict__ kb, short* __restrict__ vtb) {
  __shared__ short smem[32768];   // 2 bufs x (As 8192 | Bs 8192); epi overlay
  const int t = threadIdx.x;
  const int w = t >> 6;
  const int lane = t & 63;
  const int col = lane & 15;
  const int quad = lane >> 4;
  const int wm = w >> 1;
  const int wn = w & 1;
  const int bid = blockIdx.x;     // 0..767
  const int xcd = bid & 7;
  const int seq = bid >> 3;       // 0..95
  const int m0 = (seq / 3) * 128;
  const int n0 = (xcd * 3 + seq % 3) * 128;

  f32x4 acc[4][4] = {};

  auto stage = [&](short* As, short* Bs, int k0) {
#pragma unroll
    for (int i = 0; i < 4; i++) {  // A: 1024 chunks of 16B (128 rows x 8)
      const int c0 = i * 256 + w * 64;
      const int c = c0 + lane;
      const int row = c >> 3;
      const int gseg = (c & 7) ^ (row & 7);
      gload_lds16(&A[(m0 + row) * 1024 + k0 + gseg * 8], As + c0 * 8);
    }
#pragma unroll
    for (int i = 0; i < 4; i++) {  // B: 1024 chunks
      const int c0 = i * 256 + w * 64;
      const int c = c0 + lane;
      const int row = c >> 3;
      const int gseg = (c & 7) ^ (row & 7);
      gload_lds16(&W[(n0 + row) * 1024 + k0 + gseg * 8], Bs + c0 * 8);
    }
  };

  auto compute = [&](const short* As, const short* Bs) {
#pragma unroll
    for (int half = 0; half < 2; half++) {
      bf16x8 af[4], bfr[4];
#pragma unroll
      for (int mt = 0; mt < 4; mt++) {
        const int m = wm * 64 + mt * 16 + col;
        af[mt] =
            *(const bf16x8*)&As[m * 64 + (((quad + half * 4) ^ (m & 7)) * 8)];
      }
#pragma unroll
      for (int nt = 0; nt < 4; nt++) {
        const int n = wn * 64 + nt * 16 + col;
        bfr[nt] =
            *(const bf16x8*)&Bs[n * 64 + (((quad + half * 4) ^ (n & 7)) * 8)];
      }
#pragma unroll
      for (int mt = 0; mt < 4; mt++)
#pragma unroll
        for (int nt = 0; nt < 4; nt++)
          acc[mt][nt] = MFMA32(af[mt], bfr[nt], acc[mt][nt]);
    }
  };

  short* As0 = smem;          short* Bs0 = smem + 8192;
  short* As1 = smem + 16384;  short* Bs1 = smem + 24576;

  stage(As0, Bs0, 0);
  for (int it = 0; it < 8; it++) {
    const int k = it * 128;
    VMCNT(0); SBAR();               // waits stage(t), issued a full phase ago
    stage(As1, Bs1, k + 64);
    SCHED0();                       // pin prefetch-issue before compute
    compute(As0, Bs0);
    VMCNT(0); SBAR();
    if (it < 7) stage(As0, Bs0, k + 128);
    SCHED0();
    compute(As1, Bs1);
  }
  __syncthreads();   // all compute done everywhere; epilogue overlay valid

  const int j_base = n0 + wn * 64;    // 64-aligned -> single (c,h), uniform/wave
  const int c = j_base >> 10;
  const int h = (j_base >> 6) & 15;
  float bi[4];
#pragma unroll
  for (int nt = 0; nt < 4; nt++) bi[nt] = bias[j_base + nt * 16 + col];

  if (c < 2) {
    // ---- q/k: per-wave 16-row LDS transpose + fused RoPE + L2 norm ----
    short* dst = (c == 0) ? qb : kb;
    float* Tf = (float*)smem + w * 1088;           // 16 x 68 fp32, per wave
#pragma unroll
    for (int mt = 0; mt < 4; mt++) {
#pragma unroll
      for (int nt = 0; nt < 4; nt++)
#pragma unroll
        for (int r = 0; r < 4; r++)
          Tf[(quad * 4 + r) * 68 + nt * 16 + col] = acc[mt][nt][r] + bi[nt];
      // wave-private round trip (same-wave LDS ops are ordered)
#pragma unroll
      for (int p = 0; p < 4; p++) {
        const int rloc = p * 4 + quad;
        const int n = m0 + wm * 64 + mt * 16 + rloc;
        const int bidx = n >> 11;
        const int s = n & 2047;
        const float4 xv = *(const float4*)&Tf[rloc * 68 + col * 4];
        const float4 tc = *(const float4*)&tab[s * 64 + col * 4];
        const float e0 = xv.x * tc.y - xv.y * tc.x;
        const float o0 = xv.x * tc.x + xv.y * tc.y;
        const float e1 = xv.z * tc.w - xv.w * tc.z;
        const float o1 = xv.z * tc.z + xv.w * tc.w;
        float ss = e0 * e0 + o0 * o0 + e1 * e1 + o1 * o1;
        ss += __shfl_xor(ss, 1, 64);
        ss += __shfl_xor(ss, 2, 64);
        ss += __shfl_xor(ss, 4, 64);
        ss += __shfl_xor(ss, 8, 64);
        float scl = 1.0f / fmaxf(sqrtf(ss), 1e-12f);
        if (c == 0) scl *= SCALE_LOG2E;   // fold attn scale into stored Q
        int2 pk;
        pk.x = packbf_hu(e0 * scl, o0 * scl);
        pk.y = packbf_hu(e1 * scl, o1 * scl);
        *(int2*)&dst[((long)(bidx * 16 + h) * 2048 + s) * 64 + col * 4] = pk;
      }
      // next mt reuses Tf: same-wave in-order LDS ops, no barrier needed
    }
  } else {
    // ---- v: blocked-vt stores, b128-paired layout (one 16B slot holds the
    // two 16-key chunks of a 32-key MFMA group); int4 stores coalesced.
    const int bidx = m0 >> 11;
    const int st = ((m0 & 2047) >> 6) + wm;
    short* vbase = vtb + ((long)(bidx * 16 + h) * 32 + st) * 4096;
#pragma unroll
    for (int mtp = 0; mtp < 2; mtp++)
#pragma unroll
      for (int ntq = 0; ntq < 4; ntq++) {
        int4 pk4;
        pk4.x = packbf_hu(acc[2 * mtp][ntq][0] + bi[ntq],
                          acc[2 * mtp][ntq][1] + bi[ntq]);
        pk4.y = packbf_hu(acc[2 * mtp][ntq][2] + bi[ntq],
                          acc[2 * mtp][ntq][3] + bi[ntq]);
        pk4.z = packbf_hu(acc[2 * mtp + 1][ntq][0] + bi[ntq],
                          acc[2 * mtp + 1][ntq][1] + bi[ntq]);
        pk4.w = packbf_hu(acc[2 * mtp + 1][ntq][2] + bi[ntq],
                          acc[2 * mtp + 1][ntq][3] + bi[ntq]);
        *(int4*)&vbase[(mtp * 4 + ntq) * 512 + quad * 128 + col * 8] = pk4;
      }
  }
}

// ---------------------------------------------------------------------------
// MFMA streaming attention — EXACT round-7 form (measured 43.4us): K and V
// both LDS-staged, counted 2-buf distance-1 schedule, setprio around PV.
// ---------------------------------------------------------------------------
__global__ __launch_bounds__(512) void attn_mfma(
    const short* __restrict__ qb,  // [B,H,S,64]  (pre-scaled by SCALE*log2e)
    const short* __restrict__ kb,  // [B,H,S,64]
    const short* __restrict__ vt,  // [B,H,32 tiles,4096] blocked+paired
    short* __restrict__ ob) {      // [B,H,S,64]
  __shared__ __align__(16) char smem[65536];
  short* Ks = (short*)smem;            // [buf][grp][4096 shorts]
  short* Vs = Ks + 16384;              // (32KB offset)
  const int t = threadIdx.x;
  const int w = t >> 6;            // 0..7
  const int grp = w >> 2;          // key-split group (2 groups x 4 waves)
  const int wl = w & 3;            // wave within group
  const int lane = t & 63;
  const int col = lane & 15;
  const int quad = lane >> 4;
  const int bh = blockIdx.x;
  const int q0 = blockIdx.y * 128;
  const long hb = (long)bh * S_ * 64;
  const short* kg = kb + hb;
  const short* vg = vt + (long)bh * 64 * S_;

  bf16x8 qa[2][2];
#pragma unroll
  for (int mt2 = 0; mt2 < 2; mt2++)
#pragma unroll
    for (int h = 0; h < 2; h++)
      qa[mt2][h] = *(const bf16x8*)&qb[hb +
          (long)(q0 + wl * 32 + mt2 * 16 + col) * 64 + h * 32 + quad * 8];

  const int tt = (wl << 6) | lane;   // 0..255 within group
  int kofs[2];
#pragma unroll
  for (int i = 0; i < 2; i++) {
    const int cc = tt + 256 * i;
    kofs[i] = ((cc >> 7) * 16 + (cc & 15)) * 64 + ((cc >> 6) & 1) * 32 +
              ((cc >> 4) & 3) * 8;
  }

  short* KfL0 = Ks + grp * 4096;    // buf0 (constant offset from buf1)
  short* KfL1 = KfL0 + 8192;
  short* VfL0 = Vs + grp * 4096;
  short* VfL1 = VfL0 + 8192;

  f32x4 oacc[2][4] = {};
  f32x4 lacc[2] = {};
  const short oneb = 0x3F80;   // bf16 1.0
  const bf16x8 ones8 = {oneb, oneb, oneb, oneb, oneb, oneb, oneb, oneb};

  auto stage = [&](short* KfL, short* VfL, int kt) {
    const short* kgp = kg + (long)kt * 64;
    const short* vgp = vg + (long)(kt >> 6) * 4096;
#pragma unroll
    for (int i = 0; i < 2; i++) {
      gload_lds16(kgp + kofs[i], KfL + i * 2048 + wl * 512);
      gload_lds16(vgp + (tt + 256 * i) * 8, VfL + i * 2048 + wl * 512);
    }
  };

  auto compute = [&](const short* KfL, const short* VfL) {
#pragma unroll
    for (int ntp = 0; ntp < 2; ntp++) {
      i32x4 pw[2];
#pragma unroll
      for (int half = 0; half < 2; half++) {
        const int nt = ntp * 2 + half;
        const bf16x8 ka0 =
            *(const bf16x8*)&KfL[nt * 1024 + quad * 128 + col * 8];
        const bf16x8 ka1 =
            *(const bf16x8*)&KfL[nt * 1024 + 512 + quad * 128 + col * 8];
#pragma unroll
        for (int mt2 = 0; mt2 < 2; mt2++) {
          f32x4 z = {0.f, 0.f, 0.f, 0.f};
          z = MFMA32(ka0, qa[mt2][0], z);
          z = MFMA32(ka1, qa[mt2][1], z);
          const float e0 = EXP2(z[0]);   // scale pre-folded into Q
          const float e1 = EXP2(z[1]);
          const float e2 = EXP2(z[2]);
          const float e3 = EXP2(z[3]);
          if (half == 0) {
            pw[mt2].x = packbf_hu(e0, e1);
            pw[mt2].y = packbf_hu(e2, e3);
          } else {
            pw[mt2].z = packbf_hu(e0, e1);
            pw[mt2].w = packbf_hu(e2, e3);
          }
        }
      }
      const bf16x8 pb0 = __builtin_bit_cast(bf16x8, pw[0]);
      const bf16x8 pb1 = __builtin_bit_cast(bf16x8, pw[1]);
      lacc[0] = MFMA32(ones8, pb0, lacc[0]);   // 32-key row-sum, matrix pipe
      lacc[1] = MFMA32(ones8, pb1, lacc[1]);
      __builtin_amdgcn_s_setprio(1);           // pure-MFMA PV cluster
#pragma unroll
      for (int dt = 0; dt < 4; dt++) {
        const bf16x8 va = *(const bf16x8*)
            &VfL[(ntp * 4 + dt) * 512 + quad * 128 + col * 8];
        oacc[0][dt] = MFMA32(va, pb0, oacc[0][dt]);
        oacc[1][dt] = MFMA32(va, pb1, oacc[1][dt]);
      }
      __builtin_amdgcn_s_setprio(0);
    }
  };

  const int base = grp * 1024;
  stage(KfL0, VfL0, base);
  for (int it = 0; it < 8; it++) {       // 2 x 64-key tiles per iteration
    const int kt0 = base + it * 128;
    VMCNT(0); SBAR();                    // waits stage issued a full phase ago
    stage(KfL1, VfL1, kt0 + 64);
    SCHED0();
    compute(KfL0, VfL0);
    VMCNT(0); SBAR();
    if (it < 7) stage(KfL0, VfL0, kt0 + 128);
    SCHED0();
    compute(KfL1, VfL1);
  }
  __syncthreads();   // all waves done; staging dead -> overlay valid

  float* Ocomb = (float*)smem;                 // [128][68]
  float* lsumC = (float*)(smem + 34816);       // [128]
  if (grp == 1) {
#pragma unroll
    for (int mt2 = 0; mt2 < 2; mt2++) {
      const int qloc = wl * 32 + mt2 * 16 + col;
      if (quad == 0) lsumC[qloc] = lacc[mt2][0];
#pragma unroll
      for (int dt = 0; dt < 4; dt++)
        *(f32x4*)&Ocomb[qloc * 68 + dt * 16 + quad * 4] = oacc[mt2][dt];
    }
  }
  __syncthreads();
  if (grp == 0) {
#pragma unroll
    for (int mt2 = 0; mt2 < 2; mt2++) {
      const int qloc = wl * 32 + mt2 * 16 + col;
      const float inv = 1.0f / (lacc[mt2][0] + lsumC[qloc]);
      short* orow = ob + hb + (long)(q0 + qloc) * 64;
#pragma unroll
      for (int dt = 0; dt < 4; dt++) {
        const float4 oc = *(const float4*)&Ocomb[qloc * 68 + dt * 16 + quad * 4];
        int2 pk;
        pk.x = packbf_hu((oacc[mt2][dt][0] + oc.x) * inv,
                         (oacc[mt2][dt][1] + oc.y) * inv);
        pk.y = packbf_hu((oacc[mt2][dt][2] + oc.z) * inv,
                         (oacc[mt2][dt][3] + oc.w) * inv);
        *(int2*)&orow[dt * 16 + quad * 4] = pk;
      }
    }
  }
}

// ---------------------------------------------------------------------------
// out projection. NEW this round: the proven qkv GEMM shape — 128x128 tile,
// BK=64, 2-buf counted distance-1 — replacing the starved 64x64 tile
// (2 MFMA/KB staged -> 4 MFMA/KB). N=1024 caps the grid at 256 (1 block/CU),
// so the block carries 8 waves (2x4, wave piece 64x32) to keep 2 waves/SIMD
// of latency hiding. A-side k->(h,hd) remap carried over unchanged.
// ---------------------------------------------------------------------------
__global__ __launch_bounds__(512) void out_mfma(
    const short* __restrict__ O, const short* __restrict__ W,
    const float* __restrict__ bias, float* __restrict__ out) {
  __shared__ short smem[32768];   // 2 bufs x (As 8192 | Bs 8192) shorts
  const int t = threadIdx.x;
  const int w = t >> 6;           // 0..7
  const int lane = t & 63;
  const int col = lane & 15;
  const int quad = lane >> 4;
  const int wm = w >> 2;          // 0..1
  const int wn = w & 3;           // 0..3
  const int bid = blockIdx.x;     // 0..255
  const int xcd = bid & 7;
  const int seq = bid >> 3;       // 0..31
  const int m0 = seq * 128;
  const int n0 = xcd * 128;

  f32x4 acc[4][2] = {};

  auto stage = [&](short* As, short* Bs, int k0) {
#pragma unroll
    for (int i = 0; i < 2; i++) {   // A: 1024 chunks (128 rows x 8), 512 thr
      const int c0 = i * 512 + w * 64;
      const int c = c0 + lane;
      const int row = c >> 3;
      const int gseg = (c & 7) ^ (row & 7);
      const int n = m0 + row;
      const int bidx = n >> 11;
      const int s = n & 2047;
      const int kk = k0 + gseg * 8;
      gload_lds16(&O[((long)(bidx * 16 + (kk >> 6)) * 2048 + s) * 64 + (kk & 63)],
                  As + c0 * 8);
    }
#pragma unroll
    for (int i = 0; i < 2; i++) {   // B: 1024 chunks
      const int c0 = i * 512 + w * 64;
      const int c = c0 + lane;
      const int row = c >> 3;
      const int gseg = (c & 7) ^ (row & 7);
      gload_lds16(&W[(n0 + row) * 1024 + k0 + gseg * 8], Bs + c0 * 8);
    }
  };

  auto compute = [&](const short* As, const short* Bs) {
#pragma unroll
    for (int half = 0; half < 2; half++) {
      bf16x8 af[4], bfr[2];
#pragma unroll
      for (int mt = 0; mt < 4; mt++) {
        const int m = wm * 64 + mt * 16 + col;
        af[mt] =
            *(const bf16x8*)&As[m * 64 + (((quad + half * 4) ^ (m & 7)) * 8)];
      }
#pragma unroll
      for (int nt = 0; nt < 2; nt++) {
        const int n = wn * 32 + nt * 16 + col;
        bfr[nt] =
            *(const bf16x8*)&Bs[n * 64 + (((quad + half * 4) ^ (n & 7)) * 8)];
      }
#pragma unroll
      for (int mt = 0; mt < 4; mt++)
#pragma unroll
        for (int nt = 0; nt < 2; nt++)
          acc[mt][nt] = MFMA32(af[mt], bfr[nt], acc[mt][nt]);
    }
  };

  short* As0 = smem;          short* Bs0 = smem + 8192;
  short* As1 = smem + 16384;  short* Bs1 = smem + 24576;

  stage(As0, Bs0, 0);
  for (int it = 0; it < 8; it++) {
    const int k = it * 128;
    VMCNT(0); SBAR();
    stage(As1, Bs1, k + 64);
    SCHED0();
    compute(As0, Bs0);
    VMCNT(0); SBAR();
    if (it < 7) stage(As0, Bs0, k + 128);
    SCHED0();
    compute(As1, Bs1);
  }

  float bi[2];
#pragma unroll
  for (int nt = 0; nt < 2; nt++) bi[nt] = bias[n0 + wn * 32 + nt * 16 + col];
#pragma unroll
  for (int mt = 0; mt < 4; mt++) {
#pragma unroll
    for (int r = 0; r < 4; r++) {
      const int n = m0 + wm * 64 + mt * 16 + quad * 4 + r;
#pragma unroll
      for (int nt = 0; nt < 2; nt++)
        out[(long)n * 1024 + n0 + wn * 32 + nt * 16 + col] =
            acc[mt][nt][r] + bi[nt];
    }
  }
}

// ---------------------------------------------------------------------------
extern "C" void kernel_launch(void* const* d_in, const int* in_sizes, int n_in,
                              void* d_out, int out_size, void* d_ws,
                              size_t ws_size, hipStream_t stream) {
  const float* tokens = (const float*)d_in[0];
  const float* qkv_w = (const float*)d_in[1];
  const float* qkv_b = (const float*)d_in[2];
  const float* out_w = (const float*)d_in[3];
  const float* out_b = (const float*)d_in[4];
  float* out = (float*)d_out;

  const size_t per = (size_t)BHS * HD_;          // 4,194,304 elements
  float* tab = (float*)d_ws;                     // 2048*32*2 floats = 512 KB
  short* tok_bf = (short*)(tab + 2048 * 64);
  short* qkvw_bf = tok_bf + per;                 // 3M shorts
  short* outw_bf = qkvw_bf + 3 * per / 4;        // 1M
  short* q_bf = outw_bf + per / 4;               // 4M
  short* k_bf = q_bf + per;                      // 4M
  short* vt_bf = k_bf + per;                     // 4M (blocked layout)
  short* O_bf = vt_bf + per;                     // 4M  (~48.5 MB total)

  // 1) casts + rope table
  hipLaunchKernelGGL(prep, dim3(4128), dim3(256), 0, stream, tokens, qkv_w,
                     out_w, tok_bf, qkvw_bf, outw_bf, tab);
  // 2) QKV projection (R7-exact: BK=64 counted 2-buf) + fused RoPE/norm
  hipLaunchKernelGGL(qkv_mfma, dim3(768), dim3(256), 0, stream, tok_bf,
                     qkvw_bf, qkv_b, tab, q_bf, k_bf, vt_bf);
  // 3) Attention (R7-exact: K+V LDS, counted 2-buf, setprio)
  hipLaunchKernelGGL(attn_mfma, dim3(B_ * H_, S_ / 128), dim3(512), 0, stream,
                     q_bf, k_bf, vt_bf, O_bf);
  // 4) Output projection (NEW: 128x128 tile, 8 waves, BK=64 counted 2-buf)
  hipLaunchKernelGGL(out_mfma, dim3(256), dim3(512), 0, stream, O_bf,
                     outw_bf, out_b, out);
}

// Round 11
// 170.635 us; speedup vs baseline: 1.1832x; 1.0626x over previous
//
#include <hip/hip_runtime.h>
#include <hip/hip_bf16.h>
#include <math.h>

// Problem constants
#define B_ 2
#define S_ 2048
#define D_ 1024
#define H_ 16
#define HD_ 64
#define BHS (B_*H_*S_)          // 65536 rows of [HD]
#define NROWS (B_*S_)           // 4096 token rows

typedef __attribute__((ext_vector_type(8))) short bf16x8;
typedef __attribute__((ext_vector_type(4))) short bf16x4;
typedef __attribute__((ext_vector_type(4))) float f32x4;
typedef __attribute__((ext_vector_type(4))) int i32x4;

#ifdef __HIP_DEVICE_COMPILE__
#define EXP2(x) __builtin_amdgcn_exp2f(x)
#else
#define EXP2(x) exp2f(x)
#endif

#define MFMA32(a, b, c) __builtin_amdgcn_mfma_f32_16x16x32_bf16(a, b, c, 0, 0, 0)

// SCALE * log2(e) = 0.125 * 1.4426950408889634  (folded into stored Q)
#define SCALE_LOG2E 0.18033688011112043f

// counted-vmcnt phase primitives
#define VMCNT(N) asm volatile("s_waitcnt vmcnt(" #N ")" ::: "memory")
#define SBAR() do { __builtin_amdgcn_s_barrier(); \
                    __builtin_amdgcn_sched_barrier(0); } while (0)
#define SCHED0() __builtin_amdgcn_sched_barrier(0)

__device__ __forceinline__ short f2bf(float x) {
  __hip_bfloat16 h = __float2bfloat16(x);
  return *reinterpret_cast<short*>(&h);
}
// pack two floats to a packed bf16 pair, round-half-away: 3 VALU ops
__device__ __forceinline__ int packbf_hu(float lo, float hi) {
  unsigned lb = __float_as_uint(lo) + 0x8000u;
  unsigned hb = __float_as_uint(hi) + 0x8000u;
  return (int)__builtin_amdgcn_perm(hb, lb, 0x07060302u);
}

// async 16B global -> LDS (hardware adds lane*16 to the wave-uniform base)
__device__ __forceinline__ void gload_lds16(const short* g, short* l) {
  __builtin_amdgcn_global_load_lds(
      (const __attribute__((address_space(1))) void*)g,
      (__attribute__((address_space(3))) void*)l, 16, 0, 0);
}

// ---------------------------------------------------------------------------
// prep: fused fp32->bf16 casts (tokens, qkv_w, out_w) + RoPE sin/cos table.
// ---------------------------------------------------------------------------
__global__ __launch_bounds__(256) void prep(
    const float* __restrict__ tokens, const float* __restrict__ qkv_w,
    const float* __restrict__ out_w, short* __restrict__ tok_bf,
    short* __restrict__ qkvw_bf, short* __restrict__ outw_bf,
    float* __restrict__ tab) {
  const int i = blockIdx.x * 256 + threadIdx.x;
  const float* src;
  short* dst;
  int j;
  if (i < 524288) {
    src = tokens; dst = tok_bf; j = i;
  } else if (i < 917504) {
    src = qkv_w; dst = qkvw_bf; j = i - 524288;
  } else if (i < 1048576) {
    src = out_w; dst = outw_bf; j = i - 917504;
  } else if (i < 1056768) {
    const int e = (i - 1048576) * 8;     // entry = s*32 + f
    const int s = e >> 5;
    const int f0 = e & 31;
#pragma unroll
    for (int k = 0; k < 8; k++) {
      const int f = f0 + k;
      const float theta = (float)s * exp2f(-(float)f * 0.41524101186092034f);
      float sn, cs;
      sincosf(theta, &sn, &cs);
      tab[(s * 32 + f) * 2] = sn;
      tab[(s * 32 + f) * 2 + 1] = cs;
    }
    return;
  } else {
    return;
  }
  const float4 a = *(const float4*)(src + (long)j * 8);
  const float4 b = *(const float4*)(src + (long)j * 8 + 4);
  short tmp[8] = {f2bf(a.x), f2bf(a.y), f2bf(a.z), f2bf(a.w),
                  f2bf(b.x), f2bf(b.y), f2bf(b.z), f2bf(b.w)};
  *(bf16x8*)(dst + (long)j * 8) = *(const bf16x8*)tmp;
}

// ---------------------------------------------------------------------------
// qkv projection — R7-exact (best verified): 128x128 tile, 4 waves (2x2,
// wave piece 64x64), BK=64, 2-buf counted distance-1 schedule.
// ---------------------------------------------------------------------------
__global__ __launch_bounds__(256) void qkv_mfma(
    const short* __restrict__ A, const short* __restrict__ W,
    const float* __restrict__ bias, const float* __restrict__ tab,
    short* __restrict__ qb, short* __restrict__ kb, short* __restrict__ vtb) {
  __shared__ short smem[32768];   // 2 bufs x (As 8192 | Bs 8192); epi overlay
  const int t = threadIdx.x;
  const int w = t >> 6;
  const int lane = t & 63;
  const int col = lane & 15;
  const int quad = lane >> 4;
  const int wm = w >> 1;
  const int wn = w & 1;
  const int bid = blockIdx.x;     // 0..767
  const int xcd = bid & 7;
  const int seq = bid >> 3;       // 0..95
  const int m0 = (seq / 3) * 128;
  const int n0 = (xcd * 3 + seq % 3) * 128;

  f32x4 acc[4][4] = {};

  auto stage = [&](short* As, short* Bs, int k0) {
#pragma unroll
    for (int i = 0; i < 4; i++) {  // A: 1024 chunks of 16B (128 rows x 8)
      const int c0 = i * 256 + w * 64;
      const int c = c0 + lane;
      const int row = c >> 3;
      const int gseg = (c & 7) ^ (row & 7);
      gload_lds16(&A[(m0 + row) * 1024 + k0 + gseg * 8], As + c0 * 8);
    }
#pragma unroll
    for (int i = 0; i < 4; i++) {  // B: 1024 chunks
      const int c0 = i * 256 + w * 64;
      const int c = c0 + lane;
      const int row = c >> 3;
      const int gseg = (c & 7) ^ (row & 7);
      gload_lds16(&W[(n0 + row) * 1024 + k0 + gseg * 8], Bs + c0 * 8);
    }
  };

  auto compute = [&](const short* As, const short* Bs) {
#pragma unroll
    for (int half = 0; half < 2; half++) {
      bf16x8 af[4], bfr[4];
#pragma unroll
      for (int mt = 0; mt < 4; mt++) {
        const int m = wm * 64 + mt * 16 + col;
        af[mt] =
            *(const bf16x8*)&As[m * 64 + (((quad + half * 4) ^ (m & 7)) * 8)];
      }
#pragma unroll
      for (int nt = 0; nt < 4; nt++) {
        const int n = wn * 64 + nt * 16 + col;
        bfr[nt] =
            *(const bf16x8*)&Bs[n * 64 + (((quad + half * 4) ^ (n & 7)) * 8)];
      }
#pragma unroll
      for (int mt = 0; mt < 4; mt++)
#pragma unroll
        for (int nt = 0; nt < 4; nt++)
          acc[mt][nt] = MFMA32(af[mt], bfr[nt], acc[mt][nt]);
    }
  };

  short* As0 = smem;          short* Bs0 = smem + 8192;
  short* As1 = smem + 16384;  short* Bs1 = smem + 24576;

  stage(As0, Bs0, 0);
  for (int it = 0; it < 8; it++) {
    const int k = it * 128;
    VMCNT(0); SBAR();               // waits stage(t), issued a full phase ago
    stage(As1, Bs1, k + 64);
    SCHED0();                       // pin prefetch-issue before compute
    compute(As0, Bs0);
    VMCNT(0); SBAR();
    if (it < 7) stage(As0, Bs0, k + 128);
    SCHED0();
    compute(As1, Bs1);
  }
  __syncthreads();   // all compute done everywhere; epilogue overlay valid

  const int j_base = n0 + wn * 64;    // 64-aligned -> single (c,h), uniform/wave
  const int c = j_base >> 10;
  const int h = (j_base >> 6) & 15;
  float bi[4];
#pragma unroll
  for (int nt = 0; nt < 4; nt++) bi[nt] = bias[j_base + nt * 16 + col];

  if (c < 2) {
    // ---- q/k: per-wave 16-row LDS transpose + fused RoPE + L2 norm ----
    short* dst = (c == 0) ? qb : kb;
    float* Tf = (float*)smem + w * 1088;           // 16 x 68 fp32, per wave
#pragma unroll
    for (int mt = 0; mt < 4; mt++) {
#pragma unroll
      for (int nt = 0; nt < 4; nt++)
#pragma unroll
        for (int r = 0; r < 4; r++)
          Tf[(quad * 4 + r) * 68 + nt * 16 + col] = acc[mt][nt][r] + bi[nt];
      // wave-private round trip (same-wave LDS ops are ordered)
#pragma unroll
      for (int p = 0; p < 4; p++) {
        const int rloc = p * 4 + quad;
        const int n = m0 + wm * 64 + mt * 16 + rloc;
        const int bidx = n >> 11;
        const int s = n & 2047;
        const float4 xv = *(const float4*)&Tf[rloc * 68 + col * 4];
        const float4 tc = *(const float4*)&tab[s * 64 + col * 4];
        const float e0 = xv.x * tc.y - xv.y * tc.x;
        const float o0 = xv.x * tc.x + xv.y * tc.y;
        const float e1 = xv.z * tc.w - xv.w * tc.z;
        const float o1 = xv.z * tc.z + xv.w * tc.w;
        float ss = e0 * e0 + o0 * o0 + e1 * e1 + o1 * o1;
        ss += __shfl_xor(ss, 1, 64);
        ss += __shfl_xor(ss, 2, 64);
        ss += __shfl_xor(ss, 4, 64);
        ss += __shfl_xor(ss, 8, 64);
        float scl = 1.0f / fmaxf(sqrtf(ss), 1e-12f);
        if (c == 0) scl *= SCALE_LOG2E;   // fold attn scale into stored Q
        int2 pk;
        pk.x = packbf_hu(e0 * scl, o0 * scl);
        pk.y = packbf_hu(e1 * scl, o1 * scl);
        *(int2*)&dst[((long)(bidx * 16 + h) * 2048 + s) * 64 + col * 4] = pk;
      }
      // next mt reuses Tf: same-wave in-order LDS ops, no barrier needed
    }
  } else {
    // ---- v: blocked-vt stores, b128-paired layout (one 16B slot holds the
    // two 16-key chunks of a 32-key MFMA group); int4 stores coalesced.
    const int bidx = m0 >> 11;
    const int st = ((m0 & 2047) >> 6) + wm;
    short* vbase = vtb + ((long)(bidx * 16 + h) * 32 + st) * 4096;
#pragma unroll
    for (int mtp = 0; mtp < 2; mtp++)
#pragma unroll
      for (int ntq = 0; ntq < 4; ntq++) {
        int4 pk4;
        pk4.x = packbf_hu(acc[2 * mtp][ntq][0] + bi[ntq],
                          acc[2 * mtp][ntq][1] + bi[ntq]);
        pk4.y = packbf_hu(acc[2 * mtp][ntq][2] + bi[ntq],
                          acc[2 * mtp][ntq][3] + bi[ntq]);
        pk4.z = packbf_hu(acc[2 * mtp + 1][ntq][0] + bi[ntq],
                          acc[2 * mtp + 1][ntq][1] + bi[ntq]);
        pk4.w = packbf_hu(acc[2 * mtp + 1][ntq][2] + bi[ntq],
                          acc[2 * mtp + 1][ntq][3] + bi[ntq]);
        *(int4*)&vbase[(mtp * 4 + ntq) * 512 + quad * 128 + col * 8] = pk4;
      }
  }
}

// ---------------------------------------------------------------------------
// MFMA streaming attention — R7-exact (measured 43.4us): K and V both
// LDS-staged, counted 2-buf distance-1 schedule, setprio around PV.
// ---------------------------------------------------------------------------
__global__ __launch_bounds__(512) void attn_mfma(
    const short* __restrict__ qb,  // [B,H,S,64]  (pre-scaled by SCALE*log2e)
    const short* __restrict__ kb,  // [B,H,S,64]
    const short* __restrict__ vt,  // [B,H,32 tiles,4096] blocked+paired
    short* __restrict__ ob) {      // [B,H,S,64]
  __shared__ __align__(16) char smem[65536];
  short* Ks = (short*)smem;            // [buf][grp][4096 shorts]
  short* Vs = Ks + 16384;              // (32KB offset)
  const int t = threadIdx.x;
  const int w = t >> 6;            // 0..7
  const int grp = w >> 2;          // key-split group (2 groups x 4 waves)
  const int wl = w & 3;            // wave within group
  const int lane = t & 63;
  const int col = lane & 15;
  const int quad = lane >> 4;
  const int bh = blockIdx.x;
  const int q0 = blockIdx.y * 128;
  const long hb = (long)bh * S_ * 64;
  const short* kg = kb + hb;
  const short* vg = vt + (long)bh * 64 * S_;

  bf16x8 qa[2][2];
#pragma unroll
  for (int mt2 = 0; mt2 < 2; mt2++)
#pragma unroll
    for (int h = 0; h < 2; h++)
      qa[mt2][h] = *(const bf16x8*)&qb[hb +
          (long)(q0 + wl * 32 + mt2 * 16 + col) * 64 + h * 32 + quad * 8];

  const int tt = (wl << 6) | lane;   // 0..255 within group
  int kofs[2];
#pragma unroll
  for (int i = 0; i < 2; i++) {
    const int cc = tt + 256 * i;
    kofs[i] = ((cc >> 7) * 16 + (cc & 15)) * 64 + ((cc >> 6) & 1) * 32 +
              ((cc >> 4) & 3) * 8;
  }

  short* KfL0 = Ks + grp * 4096;    // buf0 (constant offset from buf1)
  short* KfL1 = KfL0 + 8192;
  short* VfL0 = Vs + grp * 4096;
  short* VfL1 = VfL0 + 8192;

  f32x4 oacc[2][4] = {};
  f32x4 lacc[2] = {};
  const short oneb = 0x3F80;   // bf16 1.0
  const bf16x8 ones8 = {oneb, oneb, oneb, oneb, oneb, oneb, oneb, oneb};

  auto stage = [&](short* KfL, short* VfL, int kt) {
    const short* kgp = kg + (long)kt * 64;
    const short* vgp = vg + (long)(kt >> 6) * 4096;
#pragma unroll
    for (int i = 0; i < 2; i++) {
      gload_lds16(kgp + kofs[i], KfL + i * 2048 + wl * 512);
      gload_lds16(vgp + (tt + 256 * i) * 8, VfL + i * 2048 + wl * 512);
    }
  };

  auto compute = [&](const short* KfL, const short* VfL) {
#pragma unroll
    for (int ntp = 0; ntp < 2; ntp++) {
      i32x4 pw[2];
#pragma unroll
      for (int half = 0; half < 2; half++) {
        const int nt = ntp * 2 + half;
        const bf16x8 ka0 =
            *(const bf16x8*)&KfL[nt * 1024 + quad * 128 + col * 8];
        const bf16x8 ka1 =
            *(const bf16x8*)&KfL[nt * 1024 + 512 + quad * 128 + col * 8];
#pragma unroll
        for (int mt2 = 0; mt2 < 2; mt2++) {
          f32x4 z = {0.f, 0.f, 0.f, 0.f};
          z = MFMA32(ka0, qa[mt2][0], z);
          z = MFMA32(ka1, qa[mt2][1], z);
          const float e0 = EXP2(z[0]);   // scale pre-folded into Q
          const float e1 = EXP2(z[1]);
          const float e2 = EXP2(z[2]);
          const float e3 = EXP2(z[3]);
          if (half == 0) {
            pw[mt2].x = packbf_hu(e0, e1);
            pw[mt2].y = packbf_hu(e2, e3);
          } else {
            pw[mt2].z = packbf_hu(e0, e1);
            pw[mt2].w = packbf_hu(e2, e3);
          }
        }
      }
      const bf16x8 pb0 = __builtin_bit_cast(bf16x8, pw[0]);
      const bf16x8 pb1 = __builtin_bit_cast(bf16x8, pw[1]);
      lacc[0] = MFMA32(ones8, pb0, lacc[0]);   // 32-key row-sum, matrix pipe
      lacc[1] = MFMA32(ones8, pb1, lacc[1]);
      __builtin_amdgcn_s_setprio(1);           // pure-MFMA PV cluster
#pragma unroll
      for (int dt = 0; dt < 4; dt++) {
        const bf16x8 va = *(const bf16x8*)
            &VfL[(ntp * 4 + dt) * 512 + quad * 128 + col * 8];
        oacc[0][dt] = MFMA32(va, pb0, oacc[0][dt]);
        oacc[1][dt] = MFMA32(va, pb1, oacc[1][dt]);
      }
      __builtin_amdgcn_s_setprio(0);
    }
  };

  const int base = grp * 1024;
  stage(KfL0, VfL0, base);
  for (int it = 0; it < 8; it++) {       // 2 x 64-key tiles per iteration
    const int kt0 = base + it * 128;
    VMCNT(0); SBAR();                    // waits stage issued a full phase ago
    stage(KfL1, VfL1, kt0 + 64);
    SCHED0();
    compute(KfL0, VfL0);
    VMCNT(0); SBAR();
    if (it < 7) stage(KfL0, VfL0, kt0 + 128);
    SCHED0();
    compute(KfL1, VfL1);
  }
  __syncthreads();   // all waves done; staging dead -> overlay valid

  float* Ocomb = (float*)smem;                 // [128][68]
  float* lsumC = (float*)(smem + 34816);       // [128]
  if (grp == 1) {
#pragma unroll
    for (int mt2 = 0; mt2 < 2; mt2++) {
      const int qloc = wl * 32 + mt2 * 16 + col;
      if (quad == 0) lsumC[qloc] = lacc[mt2][0];
#pragma unroll
      for (int dt = 0; dt < 4; dt++)
        *(f32x4*)&Ocomb[qloc * 68 + dt * 16 + quad * 4] = oacc[mt2][dt];
    }
  }
  __syncthreads();
  if (grp == 0) {
#pragma unroll
    for (int mt2 = 0; mt2 < 2; mt2++) {
      const int qloc = wl * 32 + mt2 * 16 + col;
      const float inv = 1.0f / (lacc[mt2][0] + lsumC[qloc]);
      short* orow = ob + hb + (long)(q0 + qloc) * 64;
#pragma unroll
      for (int dt = 0; dt < 4; dt++) {
        const float4 oc = *(const float4*)&Ocomb[qloc * 68 + dt * 16 + quad * 4];
        int2 pk;
        pk.x = packbf_hu((oacc[mt2][dt][0] + oc.x) * inv,
                         (oacc[mt2][dt][1] + oc.y) * inv);
        pk.y = packbf_hu((oacc[mt2][dt][2] + oc.z) * inv,
                         (oacc[mt2][dt][3] + oc.w) * inv);
        *(int2*)&orow[dt * 16 + quad * 4] = pk;
      }
    }
  }
}

// ---------------------------------------------------------------------------
// out projection — R7-exact: 64x64 tile, 4 waves (2x2, wave piece 32x32),
// BK=64, 2-buf counted distance-1, grid 1024 = 4 blocks/CU (beats R10's
// 128x128 @ 1 block/CU: TLP > staging density for this small GEMM).
// ---------------------------------------------------------------------------
__global__ __launch_bounds__(256) void out_mfma(
    const short* __restrict__ O, const short* __restrict__ W,
    const float* __restrict__ bias, float* __restrict__ out) {
  __shared__ short smem[16384];   // 2 bufs x (As 4096 | Bs 4096)
  const int t = threadIdx.x;
  const int w = t >> 6;
  const int lane = t & 63;
  const int col = lane & 15;
  const int quad = lane >> 4;
  const int wm = w >> 1;
  const int wn = w & 1;
  const int bid = blockIdx.x;     // 0..1023
  const int xcd = bid & 7;
  const int seq = bid >> 3;       // 0..127
  const int m0 = (seq >> 1) * 64;
  const int n0 = (xcd * 2 + (seq & 1)) * 64;

  f32x4 acc[2][2] = {};

  auto stage = [&](short* As, short* Bs, int k0) {
#pragma unroll
    for (int i = 0; i < 2; i++) {   // A: 512 chunks (64 rows x 8)
      const int c0 = i * 256 + w * 64;
      const int c = c0 + lane;
      const int row = c >> 3;
      const int gseg = (c & 7) ^ (row & 7);
      const int n = m0 + row;
      const int bidx = n >> 11;
      const int s = n & 2047;
      const int kk = k0 + gseg * 8;
      gload_lds16(&O[((long)(bidx * 16 + (kk >> 6)) * 2048 + s) * 64 + (kk & 63)],
                  As + c0 * 8);
    }
#pragma unroll
    for (int i = 0; i < 2; i++) {   // B: 512 chunks
      const int c0 = i * 256 + w * 64;
      const int c = c0 + lane;
      const int row = c >> 3;
      const int gseg = (c & 7) ^ (row & 7);
      gload_lds16(&W[(n0 + row) * 1024 + k0 + gseg * 8], Bs + c0 * 8);
    }
  };

  auto compute = [&](const short* As, const short* Bs) {
#pragma unroll
    for (int half = 0; half < 2; half++) {
      bf16x8 af[2], bfr[2];
#pragma unroll
      for (int mt = 0; mt < 2; mt++) {
        const int m = wm * 32 + mt * 16 + col;
        af[mt] =
            *(const bf16x8*)&As[m * 64 + (((quad + half * 4) ^ (m & 7)) * 8)];
      }
#pragma unroll
      for (int nt = 0; nt < 2; nt++) {
        const int n = wn * 32 + nt * 16 + col;
        bfr[nt] =
            *(const bf16x8*)&Bs[n * 64 + (((quad + half * 4) ^ (n & 7)) * 8)];
      }
#pragma unroll
      for (int mt = 0; mt < 2; mt++)
#pragma unroll
        for (int nt = 0; nt < 2; nt++)
          acc[mt][nt] = MFMA32(af[mt], bfr[nt], acc[mt][nt]);
    }
  };

  short* As0 = smem;         short* Bs0 = smem + 4096;
  short* As1 = smem + 8192;  short* Bs1 = smem + 12288;

  stage(As0, Bs0, 0);
  for (int it = 0; it < 8; it++) {
    const int k = it * 128;
    VMCNT(0); SBAR();
    stage(As1, Bs1, k + 64);
    SCHED0();
    compute(As0, Bs0);
    VMCNT(0); SBAR();
    if (it < 7) stage(As0, Bs0, k + 128);
    SCHED0();
    compute(As1, Bs1);
  }

  float bi[2];
#pragma unroll
  for (int nt = 0; nt < 2; nt++) bi[nt] = bias[n0 + wn * 32 + nt * 16 + col];
#pragma unroll
  for (int mt = 0; mt < 2; mt++) {
#pragma unroll
    for (int r = 0; r < 4; r++) {
      const int n = m0 + wm * 32 + mt * 16 + quad * 4 + r;
#pragma unroll
      for (int nt = 0; nt < 2; nt++)
        out[(long)n * 1024 + n0 + wn * 32 + nt * 16 + col] =
            acc[mt][nt][r] + bi[nt];
    }
  }
}

// ---------------------------------------------------------------------------
extern "C" void kernel_launch(void* const* d_in, const int* in_sizes, int n_in,
                              void* d_out, int out_size, void* d_ws,
                              size_t ws_size, hipStream_t stream) {
  const float* tokens = (const float*)d_in[0];
  const float* qkv_w = (const float*)d_in[1];
  const float* qkv_b = (const float*)d_in[2];
  const float* out_w = (const float*)d_in[3];
  const float* out_b = (const float*)d_in[4];
  float* out = (float*)d_out;

  const size_t per = (size_t)BHS * HD_;          // 4,194,304 elements
  float* tab = (float*)d_ws;                     // 2048*32*2 floats = 512 KB
  short* tok_bf = (short*)(tab + 2048 * 64);
  short* qkvw_bf = tok_bf + per;                 // 3M shorts
  short* outw_bf = qkvw_bf + 3 * per / 4;        // 1M
  short* q_bf = outw_bf + per / 4;               // 4M
  short* k_bf = q_bf + per;                      // 4M
  short* vt_bf = k_bf + per;                     // 4M (blocked layout)
  short* O_bf = vt_bf + per;                     // 4M  (~48.5 MB total)

  // 1) casts + rope table
  hipLaunchKernelGGL(prep, dim3(4128), dim3(256), 0, stream, tokens, qkv_w,
                     out_w, tok_bf, qkvw_bf, outw_bf, tab);
  // 2) QKV projection (R7-exact: BK=64 counted 2-buf) + fused RoPE/norm
  hipLaunchKernelGGL(qkv_mfma, dim3(768), dim3(256), 0, stream, tok_bf,
                     qkvw_bf, qkv_b, tab, q_bf, k_bf, vt_bf);
  // 3) Attention (R7-exact: K+V LDS, counted 2-buf, setprio)
  hipLaunchKernelGGL(attn_mfma, dim3(B_ * H_, S_ / 128), dim3(512), 0, stream,
                     q_bf, k_bf, vt_bf, O_bf);
  // 4) Output projection (R7-exact: 64x64, grid 1024, BK=64 counted 2-buf)
  hipLaunchKernelGGL(out_mfma, dim3(1024), dim3(256), 0, stream, O_bf,
                     outw_bf, out_b, out);
}